// Round 3
// baseline (6277.441 us; speedup 1.0000x reference)
//
#include <hip/hip_runtime.h>

// LightGCN propagation on MI355X — R2: bucket partition + LDS-accumulate SpMM.
//
// R1 post-mortem: k_place (row-level CSR scatter) = 450 us, WRITE_SIZE 370 MB
// (7.7x line amplification on random 8B writes). Fix: we never needed a full
// row sort — partition edges into 750 buckets of 200 dst-rows (LDS-binned
// placement, ~line-sized runs per bucket per block), then SpMM accumulates each
// bucket's 200x64 fp32 rows in LDS via ds_add_f32 (2 lanes/bank = conflict-free).
//
// Inputs: [2] adj_src (6M int), [3] adj_dst (6M int), [4] adj_vals (6M f32),
//         [5] user_emb (100000x64 f32), [6] item_emb (50000x64 f32).
// Output: [150000x64] f32 = (e0+e1+e2+e3)/4.

#define NUM_USERS 100000
#define NUM_ITEMS 50000
#define N_NODES   150000
#define EMB       64
#define N_EDGES   6000000

#define ROWS_PER_B 200
#define NBUCKET    750            // 150000 / 200 exactly
#define PART_BLOCKS 1024
#define CHUNK ((N_EDGES + PART_BLOCKS - 1) / PART_BLOCKS)   // 5860

constexpr int NODE_F4 = N_NODES * EMB / 4;   // 2,400,000 float4
constexpr int USER_F4 = NUM_USERS * EMB / 4;

// ---------------- bucket build ----------------

__global__ void k_zero(int* __restrict__ p, int n) {
    int i = blockIdx.x * blockDim.x + threadIdx.x;
    if (i < n) p[i] = 0;
}

__global__ __launch_bounds__(256) void k_bhist(const int* __restrict__ dst,
                                               int* __restrict__ gcnt) {
    __shared__ int cnt[NBUCKET];
    for (int i = threadIdx.x; i < NBUCKET; i += 256) cnt[i] = 0;
    __syncthreads();
    int e0 = blockIdx.x * CHUNK;
    int e1 = min(e0 + CHUNK, N_EDGES);
    for (int e = e0 + threadIdx.x; e < e1; e += 256)
        atomicAdd(&cnt[dst[e] / ROWS_PER_B], 1);
    __syncthreads();
    for (int i = threadIdx.x; i < NBUCKET; i += 256)
        if (cnt[i]) atomicAdd(&gcnt[i], cnt[i]);
}

// one block of 1024: exclusive scan over NBUCKET counts -> boff + cursor init
__global__ void k_bscan(const int* __restrict__ gcnt, int* __restrict__ boff,
                        int* __restrict__ gcur) {
    __shared__ int s[1024];
    int t = threadIdx.x;
    int x = (t < NBUCKET) ? gcnt[t] : 0;
    s[t] = x;
    __syncthreads();
    for (int off = 1; off < 1024; off <<= 1) {
        int v = (t >= off) ? s[t - off] : 0;
        __syncthreads();
        s[t] += v;
        __syncthreads();
    }
    if (t < NBUCKET) { int ex = s[t] - x; boff[t] = ex; gcur[t] = ex; }
    if (t == 0) boff[NBUCKET] = N_EDGES;
}

// partition: per-block LDS histogram -> one global reservation per (block,bucket)
// -> LDS-cursor placement. Entry: x = src | (dstLocal<<18), y = val bits.
__global__ __launch_bounds__(256) void k_part(const int* __restrict__ src,
                                              const int* __restrict__ dst,
                                              const float* __restrict__ val,
                                              int* __restrict__ gcur,
                                              int2* __restrict__ pairs) {
    __shared__ int cnt[NBUCKET];
    __shared__ int base[NBUCKET];
    for (int i = threadIdx.x; i < NBUCKET; i += 256) cnt[i] = 0;
    __syncthreads();
    int e0 = blockIdx.x * CHUNK;
    int e1 = min(e0 + CHUNK, N_EDGES);
    for (int e = e0 + threadIdx.x; e < e1; e += 256)
        atomicAdd(&cnt[dst[e] / ROWS_PER_B], 1);
    __syncthreads();
    for (int i = threadIdx.x; i < NBUCKET; i += 256) {
        int c = cnt[i];
        base[i] = c ? atomicAdd(&gcur[i], c) : 0;
        cnt[i] = 0;
    }
    __syncthreads();
    for (int e = e0 + threadIdx.x; e < e1; e += 256) {
        int d = dst[e];
        int b = d / ROWS_PER_B;
        int dL = d - b * ROWS_PER_B;
        int off = atomicAdd(&cnt[b], 1);
        pairs[base[b] + off] = make_int2(src[e] | (dL << 18), __float_as_int(val[e]));
    }
}

// ---------------- propagation ----------------

__global__ void k_init(const float4* __restrict__ ue, const float4* __restrict__ ie,
                       float4* __restrict__ cur, float4* __restrict__ acc) {
    int i = blockIdx.x * blockDim.x + threadIdx.x;
    if (i >= NODE_F4) return;
    float4 v = (i < USER_F4) ? ue[i] : ie[i - USER_F4];
    cur[i] = v;
    acc[i] = v;
}

// one block per bucket: 200x64 fp32 accumulator in LDS (51200 B, 3 blocks/CU).
// Per wave-iter: 4 edges x 16 lanes; lane gathers one float4 of cur[src]
// (256B coalesced per 16-lane group) and does 4 ds_add_f32.
__global__ __launch_bounds__(256) void k_spmm_lds(const int* __restrict__ boff,
                                                  const int2* __restrict__ pairs,
                                                  const float4* __restrict__ cur,
                                                  float4* __restrict__ nxt,
                                                  float4* __restrict__ acc,
                                                  float s) {
    __shared__ float am[ROWS_PER_B * EMB];   // 51200 B
    int b = blockIdx.x;
    float4* am4 = (float4*)am;
    for (int i = threadIdx.x; i < ROWS_PER_B * 16; i += 256)
        am4[i] = make_float4(0.f, 0.f, 0.f, 0.f);
    __syncthreads();

    int beg = boff[b];
    int end = boff[b + 1];
    int g = threadIdx.x >> 4;     // edge slot 0..15 within block
    int c = threadIdx.x & 15;     // float4 channel within row

    for (int e = beg + g; e < end; e += 16) {
        int2 p = pairs[e];
        int srcRow = p.x & 0x3FFFF;
        int dL = p.x >> 18;
        float v = __int_as_float(p.y);
        float4 m = cur[(long)srcRow * 16 + c];
        float* a = am + dL * EMB + c * 4;
        atomicAdd(a + 0, v * m.x);
        atomicAdd(a + 1, v * m.y);
        atomicAdd(a + 2, v * m.z);
        atomicAdd(a + 3, v * m.w);
    }
    __syncthreads();

    // writeback rows [b*200, (b+1)*200): nxt = r; acc = (acc + r) * s
    long rbase = (long)b * ROWS_PER_B * 16;
    for (int i = threadIdx.x; i < ROWS_PER_B * 16; i += 256) {
        float4 r = am4[i];
        long o = rbase + i;
        nxt[o] = r;
        float4 a2 = acc[o];
        a2.x = (a2.x + r.x) * s;
        a2.y = (a2.y + r.y) * s;
        a2.z = (a2.z + r.z) * s;
        a2.w = (a2.w + r.w) * s;
        acc[o] = a2;
    }
}

// ---------------- R0 fallback (atomic scatter) for small ws ----------------

__global__ void lgcn_init(const float4* __restrict__ user_emb,
                          const float4* __restrict__ item_emb,
                          float4* __restrict__ cur, float4* __restrict__ nxt,
                          float4* __restrict__ acc) {
    int i = blockIdx.x * blockDim.x + threadIdx.x;
    if (i >= NODE_F4) return;
    float4 v = (i < USER_F4) ? user_emb[i] : item_emb[i - USER_F4];
    cur[i] = v; acc[i] = v; nxt[i] = make_float4(0.f, 0.f, 0.f, 0.f);
}

__global__ void lgcn_scatter(const int* __restrict__ src, const int* __restrict__ dst,
                             const float* __restrict__ val,
                             const float4* __restrict__ cur, float* __restrict__ nxt) {
    int tid = blockIdx.x * blockDim.x + threadIdx.x;
    int e = tid >> 4;
    if (e >= N_EDGES) return;
    int c = tid & 15;
    int s = src[e]; int d = dst[e]; float v = val[e];
    float4 m = cur[(long)s * 16 + c];
    float* p = nxt + (long)d * 64 + c * 4;
    unsafeAtomicAdd(p + 0, v * m.x);
    unsafeAtomicAdd(p + 1, v * m.y);
    unsafeAtomicAdd(p + 2, v * m.z);
    unsafeAtomicAdd(p + 3, v * m.w);
}

__global__ void lgcn_add_zero(float4* __restrict__ acc, const float4* __restrict__ nxt,
                              float4* __restrict__ other) {
    int i = blockIdx.x * blockDim.x + threadIdx.x;
    if (i >= NODE_F4) return;
    float4 a = acc[i]; float4 n = nxt[i];
    a.x += n.x; a.y += n.y; a.z += n.z; a.w += n.w;
    acc[i] = a;
    other[i] = make_float4(0.f, 0.f, 0.f, 0.f);
}

__global__ void lgcn_final(float4* __restrict__ acc, const float4* __restrict__ nxt) {
    int i = blockIdx.x * blockDim.x + threadIdx.x;
    if (i >= NODE_F4) return;
    float4 a = acc[i]; float4 n = nxt[i];
    a.x = (a.x + n.x) * 0.25f; a.y = (a.y + n.y) * 0.25f;
    a.z = (a.z + n.z) * 0.25f; a.w = (a.w + n.w) * 0.25f;
    acc[i] = a;
}

// ---------------- launch ----------------

extern "C" void kernel_launch(void* const* d_in, const int* in_sizes, int n_in,
                              void* d_out, int out_size, void* d_ws, size_t ws_size,
                              hipStream_t stream) {
    const int*    adj_src  = (const int*)d_in[2];
    const int*    adj_dst  = (const int*)d_in[3];
    const float*  adj_vals = (const float*)d_in[4];
    const float4* user_emb = (const float4*)d_in[5];
    const float4* item_emb = (const float4*)d_in[6];
    float* acc = (float*)d_out;

    const int BLK = 256;
    const int grid_node = (NODE_F4 + BLK - 1) / BLK;   // 9375

    // workspace layout (bytes)
    const size_t SZ_NODE  = (size_t)N_NODES * EMB * sizeof(float);  // 38,400,000
    const size_t SZ_PAIRS = (size_t)N_EDGES * 8;                    // 48,000,000
    const size_t SZ_BOFF  = (size_t)(NBUCKET + 1) * sizeof(int);
    const size_t SZ_BCNT  = (size_t)NBUCKET * sizeof(int);
    const size_t NEEDED = 2 * SZ_NODE + SZ_PAIRS + SZ_BOFF + 2 * SZ_BCNT + 64;

    if (ws_size >= NEEDED) {
        char* w = (char*)d_ws;
        float* cur   = (float*)(w);
        float* nxt   = (float*)(w + SZ_NODE);
        int2*  pairs = (int2*)(w + 2 * SZ_NODE);
        int*   boff  = (int*)(w + 2 * SZ_NODE + SZ_PAIRS);
        int*   gcnt  = (int*)(w + 2 * SZ_NODE + SZ_PAIRS + SZ_BOFF);
        int*   gcur  = (int*)(w + 2 * SZ_NODE + SZ_PAIRS + SZ_BOFF + SZ_BCNT);

        // bucket build
        k_zero<<<(NBUCKET + BLK - 1) / BLK, BLK, 0, stream>>>(gcnt, NBUCKET);
        k_bhist<<<PART_BLOCKS, BLK, 0, stream>>>(adj_dst, gcnt);
        k_bscan<<<1, 1024, 0, stream>>>(gcnt, boff, gcur);
        k_part<<<PART_BLOCKS, BLK, 0, stream>>>(adj_src, adj_dst, adj_vals, gcur, pairs);

        // propagation
        k_init<<<grid_node, BLK, 0, stream>>>(user_emb, item_emb, (float4*)cur, (float4*)acc);
        k_spmm_lds<<<NBUCKET, BLK, 0, stream>>>(boff, pairs, (const float4*)cur,
                                                (float4*)nxt, (float4*)acc, 1.0f);
        k_spmm_lds<<<NBUCKET, BLK, 0, stream>>>(boff, pairs, (const float4*)nxt,
                                                (float4*)cur, (float4*)acc, 1.0f);
        k_spmm_lds<<<NBUCKET, BLK, 0, stream>>>(boff, pairs, (const float4*)cur,
                                                (float4*)nxt, (float4*)acc, 0.25f);
    } else {
        // R0 fallback: atomic scatter (ws too small)
        float* ws0 = (float*)d_ws;
        float* ws1 = ws0 + (size_t)N_NODES * EMB;
        lgcn_init<<<grid_node, BLK, 0, stream>>>(user_emb, item_emb,
                                                 (float4*)ws0, (float4*)ws1, (float4*)acc);
        lgcn_scatter<<<(N_EDGES*16+BLK-1)/BLK, BLK, 0, stream>>>(adj_src, adj_dst, adj_vals,
                                                    (const float4*)ws0, ws1);
        lgcn_add_zero<<<grid_node, BLK, 0, stream>>>((float4*)acc, (const float4*)ws1, (float4*)ws0);
        lgcn_scatter<<<(N_EDGES*16+BLK-1)/BLK, BLK, 0, stream>>>(adj_src, adj_dst, adj_vals,
                                                    (const float4*)ws1, ws0);
        lgcn_add_zero<<<grid_node, BLK, 0, stream>>>((float4*)acc, (const float4*)ws0, (float4*)ws1);
        lgcn_scatter<<<(N_EDGES*16+BLK-1)/BLK, BLK, 0, stream>>>(adj_src, adj_dst, adj_vals,
                                                    (const float4*)ws0, ws1);
        lgcn_final<<<grid_node, BLK, 0, stream>>>((float4*)acc, (const float4*)ws1);
    }
}

// Round 4
// 758.179 us; speedup vs baseline: 8.2796x; 8.2796x over previous
//
#include <hip/hip_runtime.h>

// LightGCN propagation on MI355X — R3: bucket partition + per-bucket counting
// sort -> row-sorted CSR -> register-accumulate SpMM with bf16 gathers.
//
// R2 post-mortem: LDS *float* atomicAdd = CAS loop (1988 us/layer, VALUBusy 1.6%).
// LDS *int* atomics are native ds_add_u32 (k_bhist/k_part were fast). So:
//   phase 1: bucket partition (750 buckets x 200 rows) — R2's k_part, low write amp
//   phase 2: per-bucket counting sort (LDS int cursors, writes stay in 64KB window)
//   phase 3: R1-style row-gather SpMM, fp32 register accumulate, bf16 cur/nxt
//            (halves gather traffic 1.54 GB -> 768 MB/layer; acc stays fp32)
// pairs1 is dead after phase 2 -> bf16 node buffers alias it (ws ~97 MB).
//
// Inputs: [2] adj_src (6M int), [3] adj_dst (6M int), [4] adj_vals (6M f32),
//         [5] user_emb (100000x64 f32), [6] item_emb (50000x64 f32).
// Output: [150000x64] f32 = (e0+e1+e2+e3)/4.

#define NUM_USERS 100000
#define NUM_ITEMS 50000
#define N_NODES   150000
#define EMB       64
#define N_EDGES   6000000

#define ROWS_PER_B 200
#define NBUCKET    750            // 150000 / 200
#define PART_BLOCKS 1024
#define CHUNK ((N_EDGES + PART_BLOCKS - 1) / PART_BLOCKS)   // 5860

constexpr int NODE_F4 = N_NODES * EMB / 4;   // 2,400,000
constexpr int USER_F4 = NUM_USERS * EMB / 4; // 1,600,000

__device__ __forceinline__ float bf2f(unsigned short u) {
    union { unsigned int i; float f; } x; x.i = ((unsigned int)u) << 16; return x.f;
}
__device__ __forceinline__ unsigned short f2bf(float f) {
    union { float f; unsigned int i; } x; x.f = f;
    unsigned int b = x.i;
    return (unsigned short)((b + 0x7FFFu + ((b >> 16) & 1u)) >> 16);  // RNE
}

// ---------------- phase 1: bucket partition ----------------

__global__ void k_zero(int* __restrict__ p, int n) {
    int i = blockIdx.x * blockDim.x + threadIdx.x;
    if (i < n) p[i] = 0;
}

__global__ __launch_bounds__(256) void k_bhist(const int* __restrict__ dst,
                                               int* __restrict__ gcnt) {
    __shared__ int cnt[NBUCKET];
    for (int i = threadIdx.x; i < NBUCKET; i += 256) cnt[i] = 0;
    __syncthreads();
    int e0 = blockIdx.x * CHUNK;
    int e1 = min(e0 + CHUNK, N_EDGES);
    for (int e = e0 + threadIdx.x; e < e1; e += 256)
        atomicAdd(&cnt[dst[e] / ROWS_PER_B], 1);          // native ds_add_u32
    __syncthreads();
    for (int i = threadIdx.x; i < NBUCKET; i += 256)
        if (cnt[i]) atomicAdd(&gcnt[i], cnt[i]);
}

__global__ void k_bscan(const int* __restrict__ gcnt, int* __restrict__ boff,
                        int* __restrict__ gcur) {
    __shared__ int s[1024];
    int t = threadIdx.x;
    int x = (t < NBUCKET) ? gcnt[t] : 0;
    s[t] = x;
    __syncthreads();
    for (int off = 1; off < 1024; off <<= 1) {
        int v = (t >= off) ? s[t - off] : 0;
        __syncthreads();
        s[t] += v;
        __syncthreads();
    }
    if (t < NBUCKET) { int ex = s[t] - x; boff[t] = ex; gcur[t] = ex; }
    if (t == 0) boff[NBUCKET] = N_EDGES;
}

// entry: x = src | (dstLocal<<18)  (src<2^18, dstLocal<200), y = val bits
__global__ __launch_bounds__(256) void k_part(const int* __restrict__ src,
                                              const int* __restrict__ dst,
                                              const float* __restrict__ val,
                                              int* __restrict__ gcur,
                                              int2* __restrict__ pairs) {
    __shared__ int cnt[NBUCKET];
    __shared__ int base[NBUCKET];
    for (int i = threadIdx.x; i < NBUCKET; i += 256) cnt[i] = 0;
    __syncthreads();
    int e0 = blockIdx.x * CHUNK;
    int e1 = min(e0 + CHUNK, N_EDGES);
    for (int e = e0 + threadIdx.x; e < e1; e += 256)
        atomicAdd(&cnt[dst[e] / ROWS_PER_B], 1);
    __syncthreads();
    for (int i = threadIdx.x; i < NBUCKET; i += 256) {
        int c = cnt[i];
        base[i] = c ? atomicAdd(&gcur[i], c) : 0;
        cnt[i] = 0;
    }
    __syncthreads();
    for (int e = e0 + threadIdx.x; e < e1; e += 256) {
        int d = dst[e];
        int b = d / ROWS_PER_B;
        int dL = d - b * ROWS_PER_B;
        int off = atomicAdd(&cnt[b], 1);
        pairs[base[b] + off] = make_int2(src[e] | (dL << 18), __float_as_int(val[e]));
    }
}

// ---------------- phase 2: per-bucket counting sort ----------------

__global__ __launch_bounds__(256) void k_sort(const int* __restrict__ boff,
                                              const int2* __restrict__ pairs1,
                                              int2* __restrict__ pairs2,
                                              int* __restrict__ row_ptr) {
    __shared__ int cnt[ROWS_PER_B];
    __shared__ int cursor[ROWS_PER_B];
    __shared__ int s[256];
    int b = blockIdx.x;
    int beg = boff[b], end = boff[b + 1];
    int t = threadIdx.x;
    if (t < ROWS_PER_B) cnt[t] = 0;
    __syncthreads();
    for (int e = beg + t; e < end; e += 256)
        atomicAdd(&cnt[pairs1[e].x >> 18], 1);            // native int LDS atomic
    __syncthreads();
    int x = (t < ROWS_PER_B) ? cnt[t] : 0;
    s[t] = x;
    __syncthreads();
    for (int off = 1; off < 256; off <<= 1) {
        int v = (t >= off) ? s[t - off] : 0;
        __syncthreads();
        s[t] += v;
        __syncthreads();
    }
    if (t < ROWS_PER_B) {
        int ex = beg + s[t] - x;                          // exclusive prefix
        cursor[t] = ex;
        row_ptr[b * ROWS_PER_B + t] = ex;
    }
    if (b == NBUCKET - 1 && t == 0) row_ptr[N_NODES] = N_EDGES;
    __syncthreads();
    for (int e = beg + t; e < end; e += 256) {
        int2 p = pairs1[e];
        int r = p.x >> 18;
        int pos = atomicAdd(&cursor[r], 1);
        pairs2[pos] = make_int2(p.x & 0x3FFFF, p.y);      // writes within ~64KB window
    }
}

// ---------------- phase 3: propagation ----------------

__global__ void k_init(const float4* __restrict__ ue, const float4* __restrict__ ie,
                       ushort4* __restrict__ curb, float4* __restrict__ acc) {
    int i = blockIdx.x * blockDim.x + threadIdx.x;
    if (i >= NODE_F4) return;
    float4 v = (i < USER_F4) ? ue[i] : ie[i - USER_F4];
    acc[i] = v;
    curb[i] = make_ushort4(f2bf(v.x), f2bf(v.y), f2bf(v.z), f2bf(v.w));
}

// 16 lanes per dst row; lane owns 4 channels. bf16 gather (128B/edge),
// fp32 register accumulate; nxt bf16, acc fp32: acc = (acc + r) * s.
__global__ __launch_bounds__(256) void k_spmm(const int* __restrict__ row_ptr,
                                              const int2* __restrict__ pairs,
                                              const ushort4* __restrict__ cur,
                                              ushort4* __restrict__ nxt,
                                              float4* __restrict__ acc, float s) {
    int tid = blockIdx.x * blockDim.x + threadIdx.x;
    int row = tid >> 4;
    if (row >= N_NODES) return;
    int c = tid & 15;
    int beg = row_ptr[row];
    int end = row_ptr[row + 1];
    float4 r = make_float4(0.f, 0.f, 0.f, 0.f);
    int k = beg;
    for (; k + 1 < end; k += 2) {
        int2 p0 = pairs[k];
        int2 p1 = pairs[k + 1];
        ushort4 g0 = cur[(long)p0.x * 16 + c];
        ushort4 g1 = cur[(long)p1.x * 16 + c];
        float v0 = __int_as_float(p0.y);
        float v1 = __int_as_float(p1.y);
        r.x += v0 * bf2f(g0.x) + v1 * bf2f(g1.x);
        r.y += v0 * bf2f(g0.y) + v1 * bf2f(g1.y);
        r.z += v0 * bf2f(g0.z) + v1 * bf2f(g1.z);
        r.w += v0 * bf2f(g0.w) + v1 * bf2f(g1.w);
    }
    if (k < end) {
        int2 p0 = pairs[k];
        ushort4 g0 = cur[(long)p0.x * 16 + c];
        float v0 = __int_as_float(p0.y);
        r.x += v0 * bf2f(g0.x);
        r.y += v0 * bf2f(g0.y);
        r.z += v0 * bf2f(g0.z);
        r.w += v0 * bf2f(g0.w);
    }
    long o = (long)row * 16 + c;
    nxt[o] = make_ushort4(f2bf(r.x), f2bf(r.y), f2bf(r.z), f2bf(r.w));
    float4 a = acc[o];
    a.x = (a.x + r.x) * s;
    a.y = (a.y + r.y) * s;
    a.z = (a.z + r.z) * s;
    a.w = (a.w + r.w) * s;
    acc[o] = a;
}

// ---------------- R0 fallback (atomic scatter) for small ws ----------------

__global__ void lgcn_init(const float4* __restrict__ user_emb,
                          const float4* __restrict__ item_emb,
                          float4* __restrict__ cur, float4* __restrict__ nxt,
                          float4* __restrict__ acc) {
    int i = blockIdx.x * blockDim.x + threadIdx.x;
    if (i >= NODE_F4) return;
    float4 v = (i < USER_F4) ? user_emb[i] : item_emb[i - USER_F4];
    cur[i] = v; acc[i] = v; nxt[i] = make_float4(0.f, 0.f, 0.f, 0.f);
}

__global__ void lgcn_scatter(const int* __restrict__ src, const int* __restrict__ dst,
                             const float* __restrict__ val,
                             const float4* __restrict__ cur, float* __restrict__ nxt) {
    int tid = blockIdx.x * blockDim.x + threadIdx.x;
    int e = tid >> 4;
    if (e >= N_EDGES) return;
    int c = tid & 15;
    int s = src[e]; int d = dst[e]; float v = val[e];
    float4 m = cur[(long)s * 16 + c];
    float* p = nxt + (long)d * 64 + c * 4;
    unsafeAtomicAdd(p + 0, v * m.x);
    unsafeAtomicAdd(p + 1, v * m.y);
    unsafeAtomicAdd(p + 2, v * m.z);
    unsafeAtomicAdd(p + 3, v * m.w);
}

__global__ void lgcn_add_zero(float4* __restrict__ acc, const float4* __restrict__ nxt,
                              float4* __restrict__ other) {
    int i = blockIdx.x * blockDim.x + threadIdx.x;
    if (i >= NODE_F4) return;
    float4 a = acc[i]; float4 n = nxt[i];
    a.x += n.x; a.y += n.y; a.z += n.z; a.w += n.w;
    acc[i] = a;
    other[i] = make_float4(0.f, 0.f, 0.f, 0.f);
}

__global__ void lgcn_final(float4* __restrict__ acc, const float4* __restrict__ nxt) {
    int i = blockIdx.x * blockDim.x + threadIdx.x;
    if (i >= NODE_F4) return;
    float4 a = acc[i]; float4 n = nxt[i];
    a.x = (a.x + n.x) * 0.25f; a.y = (a.y + n.y) * 0.25f;
    a.z = (a.z + n.z) * 0.25f; a.w = (a.w + n.w) * 0.25f;
    acc[i] = a;
}

// ---------------- launch ----------------

extern "C" void kernel_launch(void* const* d_in, const int* in_sizes, int n_in,
                              void* d_out, int out_size, void* d_ws, size_t ws_size,
                              hipStream_t stream) {
    const int*    adj_src  = (const int*)d_in[2];
    const int*    adj_dst  = (const int*)d_in[3];
    const float*  adj_vals = (const float*)d_in[4];
    const float4* user_emb = (const float4*)d_in[5];
    const float4* item_emb = (const float4*)d_in[6];
    float* acc = (float*)d_out;

    const int BLK = 256;
    const int grid_node  = (NODE_F4 + BLK - 1) / BLK;        // 9375
    const int grid_row16 = (N_NODES * 16 + BLK - 1) / BLK;   // 9375

    // workspace layout (bytes). pairs1 is dead after k_sort -> cur/nxt alias it.
    const size_t SZ_PAIRS = (size_t)N_EDGES * 8;             // 48,000,000
    const size_t SZ_BF    = (size_t)N_NODES * EMB * 2;       // 19,200,000
    const size_t SZ_RP    = 600064;                          // 150001 ints, padded
    const size_t SZ_B     = 4096;                            // bucket arrays, padded
    const size_t NEEDED   = SZ_PAIRS + SZ_PAIRS + SZ_RP + 3 * SZ_B;  // ~96.6 MB

    if (ws_size >= NEEDED) {
        char* w = (char*)d_ws;
        int2*    pairs2  = (int2*)(w);
        int2*    pairs1  = (int2*)(w + SZ_PAIRS);
        ushort4* curb    = (ushort4*)(w + SZ_PAIRS);          // aliases pairs1
        ushort4* nxtb    = (ushort4*)(w + SZ_PAIRS + SZ_BF);  // aliases pairs1[2.4M..]
        int*     row_ptr = (int*)(w + 2 * SZ_PAIRS);
        int*     gcnt    = (int*)(w + 2 * SZ_PAIRS + SZ_RP);
        int*     gcur    = (int*)(w + 2 * SZ_PAIRS + SZ_RP + SZ_B);
        int*     boff    = (int*)(w + 2 * SZ_PAIRS + SZ_RP + 2 * SZ_B);

        // phase 1: bucket partition
        k_zero<<<(NBUCKET + BLK - 1) / BLK, BLK, 0, stream>>>(gcnt, NBUCKET);
        k_bhist<<<PART_BLOCKS, BLK, 0, stream>>>(adj_dst, gcnt);
        k_bscan<<<1, 1024, 0, stream>>>(gcnt, boff, gcur);
        k_part<<<PART_BLOCKS, BLK, 0, stream>>>(adj_src, adj_dst, adj_vals, gcur, pairs1);

        // phase 2: per-bucket counting sort -> row-sorted pairs2 + row_ptr
        k_sort<<<NBUCKET, BLK, 0, stream>>>(boff, pairs1, pairs2, row_ptr);

        // phase 3: propagation (pairs1 region now reused for bf16 node buffers)
        k_init<<<grid_node, BLK, 0, stream>>>(user_emb, item_emb, curb, (float4*)acc);
        k_spmm<<<grid_row16, BLK, 0, stream>>>(row_ptr, pairs2, curb, nxtb,
                                               (float4*)acc, 1.0f);
        k_spmm<<<grid_row16, BLK, 0, stream>>>(row_ptr, pairs2, nxtb, curb,
                                               (float4*)acc, 1.0f);
        k_spmm<<<grid_row16, BLK, 0, stream>>>(row_ptr, pairs2, curb, nxtb,
                                               (float4*)acc, 0.25f);
    } else {
        // R0 fallback: atomic scatter
        float* ws0 = (float*)d_ws;
        float* ws1 = ws0 + (size_t)N_NODES * EMB;
        lgcn_init<<<grid_node, BLK, 0, stream>>>(user_emb, item_emb,
                                                 (float4*)ws0, (float4*)ws1, (float4*)acc);
        lgcn_scatter<<<(N_EDGES*16+BLK-1)/BLK, BLK, 0, stream>>>(adj_src, adj_dst, adj_vals,
                                                    (const float4*)ws0, ws1);
        lgcn_add_zero<<<grid_node, BLK, 0, stream>>>((float4*)acc, (const float4*)ws1, (float4*)ws0);
        lgcn_scatter<<<(N_EDGES*16+BLK-1)/BLK, BLK, 0, stream>>>(adj_src, adj_dst, adj_vals,
                                                    (const float4*)ws1, ws0);
        lgcn_add_zero<<<grid_node, BLK, 0, stream>>>((float4*)acc, (const float4*)ws0, (float4*)ws1);
        lgcn_scatter<<<(N_EDGES*16+BLK-1)/BLK, BLK, 0, stream>>>(adj_src, adj_dst, adj_vals,
                                                    (const float4*)ws0, ws1);
        lgcn_final<<<grid_node, BLK, 0, stream>>>((float4*)acc, (const float4*)ws1);
    }
}